// Round 6
// baseline (6944.231 us; speedup 1.0000x reference)
//
#include <hip/hip_runtime.h>
#include <hip/hip_bf16.h>
#include <math.h>
#include <stdint.h>

// RNN LM forward: B=64 T=512 V=8192 E=1024 H=2048
// out = [logits (B*T*V f32) | loss (1 f32)]
#define Bb 64
#define Tt 512
#define Vv 8192
#define Ee 1024
#define Hh 2048

typedef unsigned short u16;
typedef unsigned long long u64;
typedef __attribute__((ext_vector_type(8))) short bf16x8;   // 8 bf16 = 4 VGPR (MFMA A/B frag)
typedef __attribute__((ext_vector_type(4))) float f32x4;    // MFMA C/D frag

__device__ __forceinline__ u16 f2b(float f) {               // f32 -> bf16 RNE
  unsigned u = __float_as_uint(f);
  u += 0x7FFF + ((u >> 16) & 1);
  return (u16)(u >> 16);
}
__device__ __forceinline__ float b2f(u16 h) {
  return __uint_as_float(((unsigned)h) << 16);
}
__device__ __forceinline__ u64 pack4(u16 a, u16 b, u16 c, u16 d) {
  return (u64)a | ((u64)b << 16) | ((u64)c << 32) | ((u64)d << 48);
}

// pipelined agent-coherent 16B load: issue-only (no waitcnt) — caller must
// s_waitcnt vmcnt(0) + sched_barrier before consuming. sc1 = agent scope,
// bypasses XCD-private L2 (reads the L3 coherence point directly).
__device__ __forceinline__ void gload16_sc1(bf16x8& dst, const void* addr) {
  asm volatile("global_load_dwordx4 %0, %1, off sc1"
               : "=v"(dst) : "v"(addr) : "memory");
}

__device__ __forceinline__ void gll16(const u16* g, u16* l) {
  __builtin_amdgcn_global_load_lds((__attribute__((address_space(1))) void*)g,
                                   (__attribute__((address_space(3))) void*)l, 16, 0, 0);
}

__device__ __forceinline__ float wave_max(float v) {
  #pragma unroll
  for (int d = 32; d; d >>= 1) v = fmaxf(v, __shfl_xor(v, d, 64));
  return v;
}
__device__ __forceinline__ float wave_sum(float v) {
  #pragma unroll
  for (int d = 32; d; d >>= 1) v += __shfl_xor(v, d, 64);
  return v;
}

// ---------------- prep kernels ----------------

// gather W_E rows by idx, split into bf16 hi|lo halves along K: emb2[m] = [hi(1024) | lo(1024)]
__global__ __launch_bounds__(256)
void embed_cast(const float* __restrict__ WE, const int* __restrict__ idx,
                u16* __restrict__ emb2) {
  const int m = blockIdx.x;
  const int row = idx[m];
  const float4 v = ((const float4*)(WE + (size_t)row * Ee))[threadIdx.x];
  ushort4 hi, lo;
  hi.x = f2b(v.x); lo.x = f2b(v.x - b2f(hi.x));
  hi.y = f2b(v.y); lo.y = f2b(v.y - b2f(hi.y));
  hi.z = f2b(v.z); lo.z = f2b(v.z - b2f(hi.z));
  hi.w = f2b(v.w); lo.w = f2b(v.w - b2f(hi.w));
  u16* d = emb2 + (size_t)m * 2048;
  ((ushort4*)d)[threadIdx.x] = hi;
  ((ushort4*)(d + Ee))[threadIdx.x] = lo;
}

// src[R][C] f32 -> dst[C][R<<dup] bf16 (transpose+cast hi); if dup, duplicate: [v | v]
__global__ __launch_bounds__(256)
void transpose_cast(const float* __restrict__ src, u16* __restrict__ dst,
                    int R, int C, int dup) {
  __shared__ float tile[32][33];
  const int bi = blockIdx.x;  // along C
  const int bj = blockIdx.y;  // along R
  const int tid = threadIdx.x;
  const int r  = tid >> 3;
  const int c4 = (tid & 7) * 4;
  float4 v = *(const float4*)(src + (size_t)(bj * 32 + r) * C + bi * 32 + c4);
  tile[r][c4 + 0] = v.x; tile[r][c4 + 1] = v.y;
  tile[r][c4 + 2] = v.z; tile[r][c4 + 3] = v.w;
  __syncthreads();
  const int RL = R << dup;
  ushort4 o;
  o.x = f2b(tile[c4 + 0][r]); o.y = f2b(tile[c4 + 1][r]);
  o.z = f2b(tile[c4 + 2][r]); o.w = f2b(tile[c4 + 3][r]);
  u16* d = dst + (size_t)(bi * 32 + r) * RL + bj * 32 + c4;
  *(ushort4*)d = o;
  if (dup) *(ushort4*)(d + R) = o;
}

// src[R][C] f32 -> hi[C][R], lo[C][R] bf16 (transpose + hi/lo split)
__global__ __launch_bounds__(256)
void transpose_cast_hilo(const float* __restrict__ src, u16* __restrict__ dhi,
                         u16* __restrict__ dlo, int R, int C) {
  __shared__ float tile[32][33];
  const int bi = blockIdx.x;  // along C
  const int bj = blockIdx.y;  // along R
  const int tid = threadIdx.x;
  const int r  = tid >> 3;
  const int c4 = (tid & 7) * 4;
  float4 v = *(const float4*)(src + (size_t)(bj * 32 + r) * C + bi * 32 + c4);
  tile[r][c4 + 0] = v.x; tile[r][c4 + 1] = v.y;
  tile[r][c4 + 2] = v.z; tile[r][c4 + 3] = v.w;
  __syncthreads();
  ushort4 oh, ol;
  #pragma unroll
  for (int j = 0; j < 4; ++j) {
    float x = tile[c4 + j][r];
    u16 h = f2b(x);
    ((u16*)&oh)[j] = h;
    ((u16*)&ol)[j] = f2b(x - b2f(h));
  }
  size_t off = (size_t)(bi * 32 + r) * R + bj * 32 + c4;
  *(ushort4*)(dhi + off) = oh;
  *(ushort4*)(dlo + off) = ol;
}

// h0[b] = [hi(start) | lo(start)] per batch row
__global__ __launch_bounds__(256)
void h0_init(const float* __restrict__ start, u16* __restrict__ hbuf) {
  const int b = blockIdx.x;
  #pragma unroll
  for (int j = 0; j < 8; ++j) {
    int n = threadIdx.x * 8 + j;
    float x = start[n];
    u16 hi = f2b(x);
    u16 lo = f2b(x - b2f(hi));
    hbuf[(size_t)b * 4096 + n] = hi;
    hbuf[(size_t)b * 4096 + 2048 + n] = lo;
  }
}

// ---------------- GEMM (m97-style 128x128 tile, BK=32, 4 waves) ----------------
// C[M x N] = A[M x K] * Bt[N x K]^T, bf16 inputs, f32 accum.
// MODE 0: out f32 at [row*N+col] + bias (head GEMM -> logits in d_out),
//         PLUS fused per-row softmax partials: pm/ps[row][bn] = (tilemax,
//         sum exp(x - tilemax)) over this block's 128 cols.
// MODE 1: out bf16 at [(t*B+b)*N+col] + bias, row = b*T+t  (xproj, t-major)
// XCD-aware block swizzle (T1): nwg % 8 == 0 for both call sites.
template <int MODE>
__global__ __launch_bounds__(256, 2)
void gemm_bt(const u16* __restrict__ A, const u16* __restrict__ Bt,
             const float* __restrict__ bias, void* __restrict__ outp,
             float* __restrict__ pm, float* __restrict__ ps,
             int M, int N, int K) {
  __shared__ u16 ldsA[128 * 32];
  __shared__ u16 ldsB[128 * 32];
  __shared__ float sm_[2][2][64];   // [wc][wr][row_local]  (MODE 0 partials)
  __shared__ float ss_[2][2][64];
  const int tid = threadIdx.x;
  const int lane = tid & 63;
  const int w = tid >> 6;
  const int wr = w >> 1, wc = w & 1;

  const int nwg = gridDim.x * gridDim.y;
  const int lin = blockIdx.y * gridDim.x + blockIdx.x;
  const int swz = (lin & 7) * (nwg >> 3) + (lin >> 3);
  const int bm = swz % gridDim.x;
  const int bn = swz / gridDim.x;

  const int srow = w * 32 + (lane >> 2);
  const int scol = (lane & 3) * 8;
  const u16* a0 = A + (size_t)(bm * 128 + srow) * K + scol;
  const u16* b0 = Bt + (size_t)(bn * 128 + srow) * K + scol;
  u16* lA0 = ldsA + w * 1024;
  u16* lA1 = ldsA + w * 1024 + 512;
  u16* lB0 = ldsB + w * 1024;
  u16* lB1 = ldsB + w * 1024 + 512;

  f32x4 acc[4][4];
  #pragma unroll
  for (int m = 0; m < 4; ++m)
    #pragma unroll
    for (int n = 0; n < 4; ++n)
      acc[m][n] = (f32x4){0.f, 0.f, 0.f, 0.f};

  const int nk = K >> 5;
  for (int kt = 0; kt < nk; ++kt) {
    __syncthreads();
    const u16* ak = a0 + kt * 32;
    const u16* bk = b0 + kt * 32;
    gll16(ak, lA0);
    gll16(ak + 16 * (size_t)K, lA1);
    gll16(bk, lB0);
    gll16(bk + 16 * (size_t)K, lB1);
    __syncthreads();
    bf16x8 af[4], bfr[4];
    #pragma unroll
    for (int i = 0; i < 4; ++i) {
      af[i]  = *(const bf16x8*)&ldsA[(wr * 64 + i * 16 + (lane & 15)) * 32 + (lane >> 4) * 8];
      bfr[i] = *(const bf16x8*)&ldsB[(wc * 64 + i * 16 + (lane & 15)) * 32 + (lane >> 4) * 8];
    }
    #pragma unroll
    for (int m = 0; m < 4; ++m)
      #pragma unroll
      for (int n = 0; n < 4; ++n)
        acc[m][n] = __builtin_amdgcn_mfma_f32_16x16x32_bf16(af[m], bfr[n], acc[m][n], 0, 0, 0);
  }

  // epilogue: D col = lane&15, row = (lane>>4)*4 + q
  const int r0 = bm * 128 + wr * 64 + (lane >> 4) * 4;
  const int c0 = bn * 128 + wc * 64 + (lane & 15);

  if (MODE == 0) {
    float bv[4];
    #pragma unroll
    for (int n = 0; n < 4; ++n) bv[n] = bias[c0 + n * 16];
    #pragma unroll
    for (int m = 0; m < 4; ++m) {
      #pragma unroll
      for (int q = 0; q < 4; ++q) {
        const int row = r0 + m * 16 + q;
        float v[4];
        float mx = -1e30f;
        #pragma unroll
        for (int n = 0; n < 4; ++n) {
          v[n] = acc[m][n][q] + bv[n];
          ((float*)outp)[(size_t)row * N + c0 + n * 16] = v[n];
          mx = fmaxf(mx, v[n]);
        }
        // reduce over the wave's 64 cols of this row: 4 regs + 16 col-lanes
        #pragma unroll
        for (int d = 1; d < 16; d <<= 1) mx = fmaxf(mx, __shfl_xor(mx, d, 64));
        float se = 0.f;
        #pragma unroll
        for (int n = 0; n < 4; ++n) se += expf(v[n] - mx);
        #pragma unroll
        for (int d = 1; d < 16; d <<= 1) se += __shfl_xor(se, d, 64);
        if ((lane & 15) == 0) {
          const int rl = m * 16 + (lane >> 4) * 4 + q;
          sm_[wc][wr][rl] = mx;
          ss_[wc][wr][rl] = se;
        }
      }
    }
    __syncthreads();
    if (w < 2) {   // wave w combines wc halves for rows [bm*128 + w*64, +64)
      float m0 = sm_[0][w][lane], m1 = sm_[1][w][lane];
      float s0 = ss_[0][w][lane], s1 = ss_[1][w][lane];
      float Mx = fmaxf(m0, m1);
      float S = s0 * expf(m0 - Mx) + s1 * expf(m1 - Mx);
      const int row = bm * 128 + w * 64 + lane;
      pm[(size_t)row * 64 + bn] = Mx;
      ps[(size_t)row * 64 + bn] = S;
    }
  } else {
    #pragma unroll
    for (int n = 0; n < 4; ++n) {
      const int col = c0 + n * 16;
      const float bv = bias[col];
      #pragma unroll
      for (int m = 0; m < 4; ++m) {
        #pragma unroll
        for (int q = 0; q < 4; ++q) {
          const int row = r0 + m * 16 + q;
          float v = acc[m][n][q] + bv;
          const int b = row >> 9, t = row & 511;   // row = b*T + t
          ((u16*)outp)[((size_t)t * Bb + b) * N + col] = f2b(v);
        }
      }
    }
  }
}

// ---------------- persistent recurrence scan ----------------
// 256 blocks x 512 thr (8 waves), 1 block/CU (144KB LDS).
// Block bid: group g = bid>>6 owns batch rows [16g,16g+16); colg = bid&63 owns
// H-cols [colg*32, colg*32+32). Wh hi-part in LDS for all 512 steps; Wh lo in
// VGPRs. h (hi|lo) ping-pongs in global via sc1 (direct-to-L3) accesses.
//
// ALL cross-block atomics RELAXED (r5-proven: agent-scope acq/rel emit
// whole-L2 writeback/invalidate -> ~9us/step). r6: arrival RMW counter
// (64 serialized same-address fetch_adds ~2-3us/step) replaced by a flag
// ARRAY: each block relaxed-stores generation t+1 to its own 4B slot; wave0's
// 64 lanes poll the 64 packed flags (one coalesced load/iter). Publication
// correctness: producers' sc1 h-stores complete at L3 before __syncthreads
// releases tid0's flag store; consumers' h loads issue only after their
// flag load returns >= t+1 (in-order issue within wave + s_barrier).
// Monotonic generation -> no reset race. Next-step xp prefetched between
// arrival and poll (overlaps detection latency).
__global__ __launch_bounds__(512, 2)
void rnn_scan(const u16* __restrict__ WhiT, const u16* __restrict__ WloT,
              const u16* __restrict__ xp, u16* __restrict__ hbuf,
              u16* __restrict__ hidden, unsigned* __restrict__ sync) {
  __shared__ u16 whi[65536];     // 128KB: frag(c2,kt) base (c2*64+kt)*512 u16
  __shared__ float red[4096];    // 16KB: 16 slots (frag0: w, frag1: 8+w) x 256 f32

  const int bid = blockIdx.x;
  const int g = bid >> 6;
  const int colg = bid & 63;
  const int rowbase = g * 16;
  const int col0 = colg * 32;
  const int tid = threadIdx.x;
  const int lane = tid & 63;
  const int w = tid >> 6;        // wave = K-slice index, 0..7

  // ---- preload Wh hi into LDS (one-time) ----
  for (int i = tid; i < 8192; i += 512) {
    const int ch = i & 3;
    const int cl = (i >> 2) & 15;
    const int kt = (i >> 6) & 63;
    const int c2 = (i >> 12) & 1;
    bf16x8 v = *(const bf16x8*)(WhiT + (size_t)(col0 + c2 * 16 + cl) * 2048 + kt * 32 + ch * 8);
    *(bf16x8*)&whi[(size_t)(c2 * 64 + kt) * 512 + ch * 128 + cl * 8] = v;
  }
  // ---- preload Wh lo into VGPRs (one-time): wave w covers ktG in [w*8, w*8+8) ----
  bf16x8 wlo[2][8];
  #pragma unroll
  for (int c2 = 0; c2 < 2; ++c2)
    #pragma unroll
    for (int kt = 0; kt < 8; ++kt)
      wlo[c2][kt] = *(const bf16x8*)(WloT + (size_t)(col0 + c2 * 16 + (lane & 15)) * 2048
                                     + (w * 8 + kt) * 32 + (lane >> 4) * 8);
  __syncthreads();

  unsigned* flags = sync + g * 64;      // 64 packed u32 flags per group (256B)
  bool dead = false;

  const int hrow = rowbase + (lane & 15);

  // xp prefetch for t=0 (epilogue waves only)
  ushort4 xv = {0, 0, 0, 0};
  if (w < 2)
    xv = *(const ushort4*)(xp + (size_t)hrow * 2048 + col0 + w * 16 + (lane >> 4) * 4);

  for (int t = 0; t < Tt; ++t) {
    const u16* hp = hbuf + (size_t)(t & 1) * (64 * 4096);
    u16*       hn = hbuf + (size_t)((t + 1) & 1) * (64 * 4096);

    // ---- batched h loads for this wave's K-slice: 16 x 16B, all in flight ----
    bf16x8 qh[8], ql[8];
    const u16* hb = hp + (size_t)hrow * 4096 + (lane >> 4) * 8;
    #pragma unroll
    for (int kt = 0; kt < 8; ++kt) {
      const u16* ph = hb + (w * 8 + kt) * 32;
      gload16_sc1(qh[kt], ph);           // hi half
      gload16_sc1(ql[kt], ph + 2048);    // lo half
    }
    asm volatile("s_waitcnt vmcnt(0)" ::: "memory");
    __builtin_amdgcn_sched_barrier(0);   // rule #18: pin MFMAs below the waitcnt

    f32x4 a0 = (f32x4){0.f, 0.f, 0.f, 0.f};
    f32x4 a1 = (f32x4){0.f, 0.f, 0.f, 0.f};
    #pragma unroll
    for (int kt = 0; kt < 8; ++kt) {
      const int ktG = w * 8 + kt;
      bf16x8 w0 = *(const bf16x8*)&whi[(size_t)(0 * 64 + ktG) * 512 + (lane >> 4) * 128 + (lane & 15) * 8];
      bf16x8 w1 = *(const bf16x8*)&whi[(size_t)(1 * 64 + ktG) * 512 + (lane >> 4) * 128 + (lane & 15) * 8];
      a0 = __builtin_amdgcn_mfma_f32_16x16x32_bf16(w0, qh[kt], a0, 0, 0, 0);
      a0 = __builtin_amdgcn_mfma_f32_16x16x32_bf16(w0, ql[kt], a0, 0, 0, 0);
      a0 = __builtin_amdgcn_mfma_f32_16x16x32_bf16(wlo[0][kt], qh[kt], a0, 0, 0, 0);
      a1 = __builtin_amdgcn_mfma_f32_16x16x32_bf16(w1, qh[kt], a1, 0, 0, 0);
      a1 = __builtin_amdgcn_mfma_f32_16x16x32_bf16(w1, ql[kt], a1, 0, 0, 0);
      a1 = __builtin_amdgcn_mfma_f32_16x16x32_bf16(wlo[1][kt], qh[kt], a1, 0, 0, 0);
    }

    // ---- K-reduce across waves: all waves export both frags ----
    *(f32x4*)&red[(w) * 256 + lane * 4]     = a0;   // frag0 bank: slots 0..7
    *(f32x4*)&red[(8 + w) * 256 + lane * 4] = a1;   // frag1 bank: slots 8..15
    __syncthreads();

    // ---- epilogue split: wave w<2 owns frag c2=w (cols col0+w*16 .. +16) ----
    if (w < 2) {
      f32x4 ac = (f32x4){0.f, 0.f, 0.f, 0.f};
      #pragma unroll
      for (int j = 0; j < 8; ++j)
        ac += *(const f32x4*)&red[(w * 8 + j) * 256 + lane * 4];
      const int cl0 = (lane >> 4) * 4;
      u16 hh[4], ll[4];
      #pragma unroll
      for (int qq = 0; qq < 4; ++qq) {
        float v = tanhf(ac[qq] + b2f(((const u16*)&xv)[qq]));
        hh[qq] = f2b(v); ll[qq] = f2b(v - b2f(hh[qq]));
      }
      u64 ph = pack4(hh[0], hh[1], hh[2], hh[3]);
      u64 pl = pack4(ll[0], ll[1], ll[2], ll[3]);
      u16* hd = hn + (size_t)hrow * 4096 + col0 + w * 16 + cl0;
      __hip_atomic_store((u64*)hd,          ph, __ATOMIC_RELAXED, __HIP_MEMORY_SCOPE_AGENT);
      __hip_atomic_store((u64*)(hd + 2048), pl, __ATOMIC_RELAXED, __HIP_MEMORY_SCOPE_AGENT);
      *(u64*)(hidden + ((size_t)hrow * Tt + t) * Hh + col0 + w * 16 + cl0) = ph;
    }

    // ---- group barrier: relaxed flag array (arrive in parallel, poll packed) ----
    __syncthreads();                    // drains vmcnt -> h stores complete at L3
    // prefetch next step's xp (barrier-independent; overlaps detection)
    if (w < 2 && t + 1 < Tt)
      xv = *(const ushort4*)(xp + ((size_t)(t + 1) * Bb + hrow) * 2048 + col0 + w * 16 + (lane >> 4) * 4);
    if (tid == 0)
      __hip_atomic_store(flags + colg, (unsigned)(t + 1), __ATOMIC_RELAXED, __HIP_MEMORY_SCOPE_AGENT);
    if (w == 0 && !dead) {
      const unsigned* fp = flags + lane;
      unsigned polls = 0;
      while (__hip_atomic_load(fp, __ATOMIC_RELAXED, __HIP_MEMORY_SCOPE_AGENT) < (unsigned)(t + 1)) {
        if (++polls > 4000000u) { dead = true; break; }   // anti-hang escape
      }
    }
    __syncthreads();
  }
}

// ---------------- loss ----------------

// per-row NLL from fused GEMM partials: M = max_l pm, S = sum_l ps*exp(pm-M),
// nll = M + log S - logits[r][tgt].  One wave per row.
__global__ __launch_bounds__(256)
void nll_from_partials(const float* __restrict__ pm, const float* __restrict__ ps,
                       const float* __restrict__ logits, const int* __restrict__ tgt,
                       float* __restrict__ nll) {
  const int r = blockIdx.x * 4 + (threadIdx.x >> 6);
  const int lane = threadIdx.x & 63;
  float m = pm[(size_t)r * 64 + lane];
  float s = ps[(size_t)r * 64 + lane];
  float M = wave_max(m);
  float S = wave_sum(s * expf(m - M));
  if (lane == 0) {
    const int tg = tgt[r];
    float o = 0.f;
    if (tg != -1) o = M + logf(S) - logits[(size_t)r * Vv + tg];
    nll[r] = o;
  }
}

__global__ __launch_bounds__(256)
void loss_reduce(const float* __restrict__ nll, const int* __restrict__ tgt,
                 float* __restrict__ out) {
  const int tid = threadIdx.x;
  float s = 0.f, c = 0.f;
  for (int i = tid; i < Bb * Tt; i += 256) {
    s += nll[i];
    c += (tgt[i] != -1) ? 1.f : 0.f;
  }
  s = wave_sum(s);
  c = wave_sum(c);
  __shared__ float as_[4], ac_[4];
  const int w = tid >> 6;
  if ((tid & 63) == 0) { as_[w] = s; ac_[w] = c; }
  __syncthreads();
  if (tid == 0) {
    float S = as_[0] + as_[1] + as_[2] + as_[3];
    float C = ac_[0] + ac_[1] + ac_[2] + ac_[3];
    out[0] = S / fmaxf(C, 1.f);
  }
}

// ---------------- launch ----------------

extern "C" void kernel_launch(void* const* d_in, const int* in_sizes, int n_in,
                              void* d_out, int out_size, void* d_ws, size_t ws_size,
                              hipStream_t stream) {
  const int*   idx    = (const int*)d_in[0];
  const int*   tgt    = (const int*)d_in[1];
  const float* W_E    = (const float*)d_in[2];
  const float* start  = (const float*)d_in[3];
  const float* W_xh   = (const float*)d_in[4];
  const float* b_xh   = (const float*)d_in[5];
  const float* W_head = (const float*)d_in[6];
  const float* b_head = (const float*)d_in[7];

  // workspace layout (~314 MB). emb2 (dead after GEMM1) aliases hidden.
  // pm/ps (head-GEMM softmax partials) alias xproj (dead after rnn_scan).
  char* ws = (char*)d_ws;
  u16*      emb2   = (u16*)(ws);                                  // 32768x2048 bf16 = 128MB
  u16*      hidden = (u16*)(ws);                                  // 32768x2048 bf16 (alias)
  u16*      xproj  = (u16*)(ws + (size_t)128 * 1024 * 1024);      // [T][B][H] bf16 = 128MB
  float*    pm     = (float*)(ws + (size_t)128 * 1024 * 1024);    // 32768x64 f32 = 8MB (alias)
  float*    ps     = (float*)(ws + (size_t)136 * 1024 * 1024);    // 32768x64 f32 = 8MB (alias)
  u16*      WheadT = (u16*)(ws + (size_t)256 * 1024 * 1024);      // 8192x2048 bf16 = 32MB
  u16*      WhiT   = (u16*)(ws + (size_t)288 * 1024 * 1024);      // 2048x2048 bf16 = 8MB
  u16*      WloT   = (u16*)(ws + (size_t)296 * 1024 * 1024);      // 2048x2048 bf16 = 8MB
  u16*      WxT2   = (u16*)(ws + (size_t)304 * 1024 * 1024);      // 2048x2048 bf16 = 8MB
  u16*      hbuf   = (u16*)(ws + (size_t)312 * 1024 * 1024);      // 2x64x4096 bf16 = 1MB
  float*    nll    = (float*)(ws + (size_t)313 * 1024 * 1024);    // 32768 f32 = 128KB
  unsigned* sync   = (unsigned*)(ws + (size_t)313 * 1024 * 1024 + 128 * 1024); // 1KB flags

  embed_cast<<<Bb * Tt, 256, 0, stream>>>(W_E, idx, emb2);
  transpose_cast<<<dim3(Hh / 32, Ee / 32), 256, 0, stream>>>(W_xh, WxT2, Ee, Hh, 1);
  transpose_cast_hilo<<<dim3(Hh / 32, Hh / 32), 256, 0, stream>>>(W_xh + (size_t)Ee * Hh, WhiT, WloT, Hh, Hh);
  transpose_cast<<<dim3(Vv / 32, Hh / 32), 256, 0, stream>>>(W_head, WheadT, Hh, Vv, 0);
  h0_init<<<Bb, 256, 0, stream>>>(start, hbuf);
  hipMemsetAsync(sync, 0, 1024, stream);

  // xproj = [emb_hi|emb_lo] @ [Wx;Wx] + b_xh   (K=2048 effective)
  gemm_bt<1><<<dim3(256, 16), 256, 0, stream>>>(emb2, WxT2, b_xh, xproj, nullptr, nullptr,
                                                Bb * Tt, Hh, 2048);

  // persistent scan: 256 blocks (1/CU), 512 threads, Wh resident in LDS+VGPR
  rnn_scan<<<256, 512, 0, stream>>>(WhiT, WloT, xproj, hbuf, hidden, sync);

  // logits = hidden @ W_head + b_head -> d_out, + fused softmax partials
  gemm_bt<0><<<dim3(256, 64), 256, 0, stream>>>(hidden, WheadT, b_head, d_out, pm, ps,
                                                Bb * Tt, Vv, 2048);

  nll_from_partials<<<Bb * Tt / 4, 256, 0, stream>>>(pm, ps, (const float*)d_out, tgt, nll);
  loss_reduce<<<1, 256, 0, stream>>>(nll, tgt, (float*)d_out + ((size_t)out_size - 1));
}

// Round 7
// 5831.164 us; speedup vs baseline: 1.1909x; 1.1909x over previous
//
#include <hip/hip_runtime.h>
#include <hip/hip_bf16.h>
#include <math.h>
#include <stdint.h>

// RNN LM forward: B=64 T=512 V=8192 E=1024 H=2048
// out = [logits (B*T*V f32) | loss (1 f32)]
#define Bb 64
#define Tt 512
#define Vv 8192
#define Ee 1024
#define Hh 2048

typedef unsigned short u16;
typedef unsigned long long u64;
typedef __attribute__((ext_vector_type(8))) short bf16x8;   // 8 bf16 = 4 VGPR (MFMA A/B frag)
typedef __attribute__((ext_vector_type(4))) float f32x4;    // MFMA C/D frag

__device__ __forceinline__ u16 f2b(float f) {               // f32 -> bf16 RNE
  unsigned u = __float_as_uint(f);
  u += 0x7FFF + ((u >> 16) & 1);
  return (u16)(u >> 16);
}
__device__ __forceinline__ float b2f(u16 h) {
  return __uint_as_float(((unsigned)h) << 16);
}
__device__ __forceinline__ u64 pack4(u16 a, u16 b, u16 c, u16 d) {
  return (u64)a | ((u64)b << 16) | ((u64)c << 32) | ((u64)d << 48);
}

// pipelined agent-coherent 16B load: issue-only (no waitcnt) — caller must
// s_waitcnt vmcnt(0) + sched_barrier before consuming. sc1 = agent scope,
// bypasses XCD-private L2 (reads the L3 coherence point directly).
__device__ __forceinline__ void gload16_sc1(bf16x8& dst, const void* addr) {
  asm volatile("global_load_dwordx4 %0, %1, off sc1"
               : "=v"(dst) : "v"(addr) : "memory");
}

__device__ __forceinline__ void gll16(const u16* g, u16* l) {
  __builtin_amdgcn_global_load_lds((__attribute__((address_space(1))) void*)g,
                                   (__attribute__((address_space(3))) void*)l, 16, 0, 0);
}

__device__ __forceinline__ float wave_max(float v) {
  #pragma unroll
  for (int d = 32; d; d >>= 1) v = fmaxf(v, __shfl_xor(v, d, 64));
  return v;
}
__device__ __forceinline__ float wave_sum(float v) {
  #pragma unroll
  for (int d = 32; d; d >>= 1) v += __shfl_xor(v, d, 64);
  return v;
}

// ---------------- prep kernels ----------------

// gather W_E rows by idx, split into bf16 hi|lo halves along K: emb2[m] = [hi(1024) | lo(1024)]
__global__ __launch_bounds__(256)
void embed_cast(const float* __restrict__ WE, const int* __restrict__ idx,
                u16* __restrict__ emb2) {
  const int m = blockIdx.x;
  const int row = idx[m];
  const float4 v = ((const float4*)(WE + (size_t)row * Ee))[threadIdx.x];
  ushort4 hi, lo;
  hi.x = f2b(v.x); lo.x = f2b(v.x - b2f(hi.x));
  hi.y = f2b(v.y); lo.y = f2b(v.y - b2f(hi.y));
  hi.z = f2b(v.z); lo.z = f2b(v.z - b2f(hi.z));
  hi.w = f2b(v.w); lo.w = f2b(v.w - b2f(hi.w));
  u16* d = emb2 + (size_t)m * 2048;
  ((ushort4*)d)[threadIdx.x] = hi;
  ((ushort4*)(d + Ee))[threadIdx.x] = lo;
}

// src[R][C] f32 -> dst[C][R<<dup] bf16 (transpose+cast hi); if dup, duplicate: [v | v]
__global__ __launch_bounds__(256)
void transpose_cast(const float* __restrict__ src, u16* __restrict__ dst,
                    int R, int C, int dup) {
  __shared__ float tile[32][33];
  const int bi = blockIdx.x;  // along C
  const int bj = blockIdx.y;  // along R
  const int tid = threadIdx.x;
  const int r  = tid >> 3;
  const int c4 = (tid & 7) * 4;
  float4 v = *(const float4*)(src + (size_t)(bj * 32 + r) * C + bi * 32 + c4);
  tile[r][c4 + 0] = v.x; tile[r][c4 + 1] = v.y;
  tile[r][c4 + 2] = v.z; tile[r][c4 + 3] = v.w;
  __syncthreads();
  const int RL = R << dup;
  ushort4 o;
  o.x = f2b(tile[c4 + 0][r]); o.y = f2b(tile[c4 + 1][r]);
  o.z = f2b(tile[c4 + 2][r]); o.w = f2b(tile[c4 + 3][r]);
  u16* d = dst + (size_t)(bi * 32 + r) * RL + bj * 32 + c4;
  *(ushort4*)d = o;
  if (dup) *(ushort4*)(d + R) = o;
}

// src[R][C] f32 -> hi[C][R], lo[C][R] bf16 (transpose + hi/lo split)
__global__ __launch_bounds__(256)
void transpose_cast_hilo(const float* __restrict__ src, u16* __restrict__ dhi,
                         u16* __restrict__ dlo, int R, int C) {
  __shared__ float tile[32][33];
  const int bi = blockIdx.x;  // along C
  const int bj = blockIdx.y;  // along R
  const int tid = threadIdx.x;
  const int r  = tid >> 3;
  const int c4 = (tid & 7) * 4;
  float4 v = *(const float4*)(src + (size_t)(bj * 32 + r) * C + bi * 32 + c4);
  tile[r][c4 + 0] = v.x; tile[r][c4 + 1] = v.y;
  tile[r][c4 + 2] = v.z; tile[r][c4 + 3] = v.w;
  __syncthreads();
  ushort4 oh, ol;
  #pragma unroll
  for (int j = 0; j < 4; ++j) {
    float x = tile[c4 + j][r];
    u16 h = f2b(x);
    ((u16*)&oh)[j] = h;
    ((u16*)&ol)[j] = f2b(x - b2f(h));
  }
  size_t off = (size_t)(bi * 32 + r) * R + bj * 32 + c4;
  *(ushort4*)(dhi + off) = oh;
  *(ushort4*)(dlo + off) = ol;
}

// h0[b] = [hi(start) | lo(start)] per batch row
__global__ __launch_bounds__(256)
void h0_init(const float* __restrict__ start, u16* __restrict__ hbuf) {
  const int b = blockIdx.x;
  #pragma unroll
  for (int j = 0; j < 8; ++j) {
    int n = threadIdx.x * 8 + j;
    float x = start[n];
    u16 hi = f2b(x);
    u16 lo = f2b(x - b2f(hi));
    hbuf[(size_t)b * 4096 + n] = hi;
    hbuf[(size_t)b * 4096 + 2048 + n] = lo;
  }
}

// ---------------- GEMM (m97-style 128x128 tile, BK=32, 4 waves) ----------------
// C[M x N] = A[M x K] * Bt[N x K]^T, bf16 inputs, f32 accum.
// MODE 0: out f32 at [row*N+col] + bias (head GEMM -> logits in d_out),
//         PLUS fused per-row softmax partials: pm/ps[row][bn] = (tilemax,
//         sum exp(x - tilemax)) over this block's 128 cols.
// MODE 1: out bf16 at [(t*B+b)*N+col] + bias, row = b*T+t  (xproj, t-major)
// XCD-aware block swizzle (T1): nwg % 8 == 0 for both call sites.
template <int MODE>
__global__ __launch_bounds__(256, 2)
void gemm_bt(const u16* __restrict__ A, const u16* __restrict__ Bt,
             const float* __restrict__ bias, void* __restrict__ outp,
             float* __restrict__ pm, float* __restrict__ ps,
             int M, int N, int K) {
  __shared__ u16 ldsA[128 * 32];
  __shared__ u16 ldsB[128 * 32];
  __shared__ float sm_[2][2][64];   // [wc][wr][row_local]  (MODE 0 partials)
  __shared__ float ss_[2][2][64];
  const int tid = threadIdx.x;
  const int lane = tid & 63;
  const int w = tid >> 6;
  const int wr = w >> 1, wc = w & 1;

  const int nwg = gridDim.x * gridDim.y;
  const int lin = blockIdx.y * gridDim.x + blockIdx.x;
  const int swz = (lin & 7) * (nwg >> 3) + (lin >> 3);
  const int bm = swz % gridDim.x;
  const int bn = swz / gridDim.x;

  const int srow = w * 32 + (lane >> 2);
  const int scol = (lane & 3) * 8;
  const u16* a0 = A + (size_t)(bm * 128 + srow) * K + scol;
  const u16* b0 = Bt + (size_t)(bn * 128 + srow) * K + scol;
  u16* lA0 = ldsA + w * 1024;
  u16* lA1 = ldsA + w * 1024 + 512;
  u16* lB0 = ldsB + w * 1024;
  u16* lB1 = ldsB + w * 1024 + 512;

  f32x4 acc[4][4];
  #pragma unroll
  for (int m = 0; m < 4; ++m)
    #pragma unroll
    for (int n = 0; n < 4; ++n)
      acc[m][n] = (f32x4){0.f, 0.f, 0.f, 0.f};

  const int nk = K >> 5;
  for (int kt = 0; kt < nk; ++kt) {
    __syncthreads();
    const u16* ak = a0 + kt * 32;
    const u16* bk = b0 + kt * 32;
    gll16(ak, lA0);
    gll16(ak + 16 * (size_t)K, lA1);
    gll16(bk, lB0);
    gll16(bk + 16 * (size_t)K, lB1);
    __syncthreads();
    bf16x8 af[4], bfr[4];
    #pragma unroll
    for (int i = 0; i < 4; ++i) {
      af[i]  = *(const bf16x8*)&ldsA[(wr * 64 + i * 16 + (lane & 15)) * 32 + (lane >> 4) * 8];
      bfr[i] = *(const bf16x8*)&ldsB[(wc * 64 + i * 16 + (lane & 15)) * 32 + (lane >> 4) * 8];
    }
    #pragma unroll
    for (int m = 0; m < 4; ++m)
      #pragma unroll
      for (int n = 0; n < 4; ++n)
        acc[m][n] = __builtin_amdgcn_mfma_f32_16x16x32_bf16(af[m], bfr[n], acc[m][n], 0, 0, 0);
  }

  // epilogue: D col = lane&15, row = (lane>>4)*4 + q
  const int r0 = bm * 128 + wr * 64 + (lane >> 4) * 4;
  const int c0 = bn * 128 + wc * 64 + (lane & 15);

  if (MODE == 0) {
    float bv[4];
    #pragma unroll
    for (int n = 0; n < 4; ++n) bv[n] = bias[c0 + n * 16];
    #pragma unroll
    for (int m = 0; m < 4; ++m) {
      #pragma unroll
      for (int q = 0; q < 4; ++q) {
        const int row = r0 + m * 16 + q;
        float v[4];
        float mx = -1e30f;
        #pragma unroll
        for (int n = 0; n < 4; ++n) {
          v[n] = acc[m][n][q] + bv[n];
          ((float*)outp)[(size_t)row * N + c0 + n * 16] = v[n];
          mx = fmaxf(mx, v[n]);
        }
        // reduce over the wave's 64 cols of this row: 4 regs + 16 col-lanes
        #pragma unroll
        for (int d = 1; d < 16; d <<= 1) mx = fmaxf(mx, __shfl_xor(mx, d, 64));
        float se = 0.f;
        #pragma unroll
        for (int n = 0; n < 4; ++n) se += expf(v[n] - mx);
        #pragma unroll
        for (int d = 1; d < 16; d <<= 1) se += __shfl_xor(se, d, 64);
        if ((lane & 15) == 0) {
          const int rl = m * 16 + (lane >> 4) * 4 + q;
          sm_[wc][wr][rl] = mx;
          ss_[wc][wr][rl] = se;
        }
      }
    }
    __syncthreads();
    if (w < 2) {   // wave w combines wc halves for rows [bm*128 + w*64, +64)
      float m0 = sm_[0][w][lane], m1 = sm_[1][w][lane];
      float s0 = ss_[0][w][lane], s1 = ss_[1][w][lane];
      float Mx = fmaxf(m0, m1);
      float S = s0 * expf(m0 - Mx) + s1 * expf(m1 - Mx);
      const int row = bm * 128 + w * 64 + lane;
      pm[(size_t)row * 64 + bn] = Mx;
      ps[(size_t)row * 64 + bn] = S;
    }
  } else {
    #pragma unroll
    for (int n = 0; n < 4; ++n) {
      const int col = c0 + n * 16;
      const float bv = bias[col];
      #pragma unroll
      for (int m = 0; m < 4; ++m) {
        #pragma unroll
        for (int q = 0; q < 4; ++q) {
          const int row = r0 + m * 16 + q;
          float v = acc[m][n][q] + bv;
          const int b = row >> 9, t = row & 511;   // row = b*T + t
          ((u16*)outp)[((size_t)t * Bb + b) * N + col] = f2b(v);
        }
      }
    }
  }
}

// ---------------- persistent recurrence scan ----------------
// 256 blocks x 512 thr (8 waves), 1 block/CU (144KB LDS).
// Block bid: group g = bid>>6 owns batch rows [16g,16g+16); colg = bid&63 owns
// H-cols [colg*32, colg*32+32). Wh hi-part in LDS for all 512 steps; Wh lo in
// VGPRs. h (hi|lo) ping-pongs in global via sc1 (direct-to-L3) accesses.
//
// Sync lessons (A/B-measured r2-r6):
//  * agent-scope acq/rel = whole-L2 wb/inv every step -> RELAXED everywhere (r5, -9us/step)
//  * flag-array poll (4096 lanes hammering 256B of L3) regresses (r3, r6) ->
//    single generation word polled by 64 tid0's only
//  * r7: 64-deep same-address fetch_add chain (~2-3us) -> 2-LEVEL TREE:
//    8 sub-counters (own 256B lines, parallel 8-deep chains) -> top counter
//    (8-deep) -> final leader stores gn = t+1. Monotonic, no reset race.
// Publication: producers' sc1 h-stores complete at L3 before tid0's arrival
// RMW issues (syncthreads drains vmcnt; same-wave order); consumers' h loads
// issue only after the gn poll exits (branch + s_barrier).
__global__ __launch_bounds__(512, 2)
void rnn_scan(const u16* __restrict__ WhiT, const u16* __restrict__ WloT,
              const u16* __restrict__ xp, u16* __restrict__ hbuf,
              u16* __restrict__ hidden, unsigned* __restrict__ sync) {
  __shared__ u16 whi[65536];     // 128KB: frag(c2,kt) base (c2*64+kt)*512 u16
  __shared__ float red[4096];    // 16KB: 16 slots (frag0: w, frag1: 8+w) x 256 f32

  const int bid = blockIdx.x;
  const int g = bid >> 6;
  const int colg = bid & 63;
  const int rowbase = g * 16;
  const int col0 = colg * 32;
  const int tid = threadIdx.x;
  const int lane = tid & 63;
  const int w = tid >> 6;        // wave = K-slice index, 0..7

  // ---- preload Wh hi into LDS (one-time) ----
  for (int i = tid; i < 8192; i += 512) {
    const int ch = i & 3;
    const int cl = (i >> 2) & 15;
    const int kt = (i >> 6) & 63;
    const int c2 = (i >> 12) & 1;
    bf16x8 v = *(const bf16x8*)(WhiT + (size_t)(col0 + c2 * 16 + cl) * 2048 + kt * 32 + ch * 8);
    *(bf16x8*)&whi[(size_t)(c2 * 64 + kt) * 512 + ch * 128 + cl * 8] = v;
  }
  // ---- preload Wh lo into VGPRs (one-time): wave w covers ktG in [w*8, w*8+8) ----
  bf16x8 wlo[2][8];
  #pragma unroll
  for (int c2 = 0; c2 < 2; ++c2)
    #pragma unroll
    for (int kt = 0; kt < 8; ++kt)
      wlo[c2][kt] = *(const bf16x8*)(WloT + (size_t)(col0 + c2 * 16 + (lane & 15)) * 2048
                                     + (w * 8 + kt) * 32 + (lane >> 4) * 8);
  __syncthreads();

  // arrival tree slots (u32 index, per group g): sub-counter j at g*1024+j*64,
  // top at g*1024+512, generation at g*1024+576 — all on distinct 256B lines.
  unsigned* csub = sync + g * 1024 + (colg >> 3) * 64;
  unsigned* ctop = sync + g * 1024 + 512;
  unsigned* gn   = sync + g * 1024 + 576;
  bool dead = false;

  const int hrow = rowbase + (lane & 15);

  // xp prefetch for t=0 (epilogue waves only)
  ushort4 xv = {0, 0, 0, 0};
  if (w < 2)
    xv = *(const ushort4*)(xp + (size_t)hrow * 2048 + col0 + w * 16 + (lane >> 4) * 4);

  for (int t = 0; t < Tt; ++t) {
    const u16* hp = hbuf + (size_t)(t & 1) * (64 * 4096);
    u16*       hn = hbuf + (size_t)((t + 1) & 1) * (64 * 4096);

    // ---- batched h loads for this wave's K-slice: 16 x 16B, all in flight ----
    bf16x8 qh[8], ql[8];
    const u16* hb = hp + (size_t)hrow * 4096 + (lane >> 4) * 8;
    #pragma unroll
    for (int kt = 0; kt < 8; ++kt) {
      const u16* ph = hb + (w * 8 + kt) * 32;
      gload16_sc1(qh[kt], ph);           // hi half
      gload16_sc1(ql[kt], ph + 2048);    // lo half
    }
    asm volatile("s_waitcnt vmcnt(0)" ::: "memory");
    __builtin_amdgcn_sched_barrier(0);   // rule #18: pin MFMAs below the waitcnt

    f32x4 a0 = (f32x4){0.f, 0.f, 0.f, 0.f};
    f32x4 a1 = (f32x4){0.f, 0.f, 0.f, 0.f};
    #pragma unroll
    for (int kt = 0; kt < 8; ++kt) {
      const int ktG = w * 8 + kt;
      bf16x8 w0 = *(const bf16x8*)&whi[(size_t)(0 * 64 + ktG) * 512 + (lane >> 4) * 128 + (lane & 15) * 8];
      bf16x8 w1 = *(const bf16x8*)&whi[(size_t)(1 * 64 + ktG) * 512 + (lane >> 4) * 128 + (lane & 15) * 8];
      a0 = __builtin_amdgcn_mfma_f32_16x16x32_bf16(w0, qh[kt], a0, 0, 0, 0);
      a0 = __builtin_amdgcn_mfma_f32_16x16x32_bf16(w0, ql[kt], a0, 0, 0, 0);
      a0 = __builtin_amdgcn_mfma_f32_16x16x32_bf16(wlo[0][kt], qh[kt], a0, 0, 0, 0);
      a1 = __builtin_amdgcn_mfma_f32_16x16x32_bf16(w1, qh[kt], a1, 0, 0, 0);
      a1 = __builtin_amdgcn_mfma_f32_16x16x32_bf16(w1, ql[kt], a1, 0, 0, 0);
      a1 = __builtin_amdgcn_mfma_f32_16x16x32_bf16(wlo[1][kt], qh[kt], a1, 0, 0, 0);
    }

    // ---- K-reduce across waves: all waves export both frags ----
    *(f32x4*)&red[(w) * 256 + lane * 4]     = a0;   // frag0 bank: slots 0..7
    *(f32x4*)&red[(8 + w) * 256 + lane * 4] = a1;   // frag1 bank: slots 8..15
    __syncthreads();

    // ---- epilogue split: wave w<2 owns frag c2=w (cols col0+w*16 .. +16) ----
    if (w < 2) {
      f32x4 ac = (f32x4){0.f, 0.f, 0.f, 0.f};
      #pragma unroll
      for (int j = 0; j < 8; ++j)
        ac += *(const f32x4*)&red[(w * 8 + j) * 256 + lane * 4];
      const int cl0 = (lane >> 4) * 4;
      u16 hh[4], ll[4];
      #pragma unroll
      for (int qq = 0; qq < 4; ++qq) {
        float v = tanhf(ac[qq] + b2f(((const u16*)&xv)[qq]));
        hh[qq] = f2b(v); ll[qq] = f2b(v - b2f(hh[qq]));
      }
      u64 ph = pack4(hh[0], hh[1], hh[2], hh[3]);
      u64 pl = pack4(ll[0], ll[1], ll[2], ll[3]);
      u16* hd = hn + (size_t)hrow * 4096 + col0 + w * 16 + cl0;
      __hip_atomic_store((u64*)hd,          ph, __ATOMIC_RELAXED, __HIP_MEMORY_SCOPE_AGENT);
      __hip_atomic_store((u64*)(hd + 2048), pl, __ATOMIC_RELAXED, __HIP_MEMORY_SCOPE_AGENT);
      *(u64*)(hidden + ((size_t)hrow * Tt + t) * Hh + col0 + w * 16 + cl0) = ph;
    }

    // ---- group barrier: relaxed 2-level arrival tree + generation poll ----
    __syncthreads();                    // drains vmcnt -> h stores complete at L3
    // prefetch next step's xp (barrier-independent; overlaps arrival/detect)
    if (w < 2 && t + 1 < Tt)
      xv = *(const ushort4*)(xp + ((size_t)(t + 1) * Bb + hrow) * 2048 + col0 + w * 16 + (lane >> 4) * 4);
    if (tid == 0) {
      bool final_ = false;
      unsigned old = __hip_atomic_fetch_add(csub, 1u, __ATOMIC_RELAXED, __HIP_MEMORY_SCOPE_AGENT);
      if (old == (unsigned)(t * 8 + 7)) {          // last of my 8-block sub-group
        unsigned o2 = __hip_atomic_fetch_add(ctop, 1u, __ATOMIC_RELAXED, __HIP_MEMORY_SCOPE_AGENT);
        if (o2 == (unsigned)(t * 8 + 7)) {         // last sub-group overall
          __hip_atomic_store(gn, (unsigned)(t + 1), __ATOMIC_RELAXED, __HIP_MEMORY_SCOPE_AGENT);
          final_ = true;
        }
      }
      if (!final_ && !dead) {
        unsigned polls = 0;
        while (__hip_atomic_load(gn, __ATOMIC_RELAXED, __HIP_MEMORY_SCOPE_AGENT) < (unsigned)(t + 1)) {
          if (++polls > 4000000u) { dead = true; break; }   // anti-hang escape
        }
      }
    }
    __syncthreads();
  }
}

// ---------------- loss ----------------

// per-row NLL from fused GEMM partials: M = max_l pm, S = sum_l ps*exp(pm-M),
// nll = M + log S - logits[r][tgt].  One wave per row.
__global__ __launch_bounds__(256)
void nll_from_partials(const float* __restrict__ pm, const float* __restrict__ ps,
                       const float* __restrict__ logits, const int* __restrict__ tgt,
                       float* __restrict__ nll) {
  const int r = blockIdx.x * 4 + (threadIdx.x >> 6);
  const int lane = threadIdx.x & 63;
  float m = pm[(size_t)r * 64 + lane];
  float s = ps[(size_t)r * 64 + lane];
  float M = wave_max(m);
  float S = wave_sum(s * expf(m - M));
  if (lane == 0) {
    const int tg = tgt[r];
    float o = 0.f;
    if (tg != -1) o = M + logf(S) - logits[(size_t)r * Vv + tg];
    nll[r] = o;
  }
}

__global__ __launch_bounds__(256)
void loss_reduce(const float* __restrict__ nll, const int* __restrict__ tgt,
                 float* __restrict__ out) {
  const int tid = threadIdx.x;
  float s = 0.f, c = 0.f;
  for (int i = tid; i < Bb * Tt; i += 256) {
    s += nll[i];
    c += (tgt[i] != -1) ? 1.f : 0.f;
  }
  s = wave_sum(s);
  c = wave_sum(c);
  __shared__ float as_[4], ac_[4];
  const int w = tid >> 6;
  if ((tid & 63) == 0) { as_[w] = s; ac_[w] = c; }
  __syncthreads();
  if (tid == 0) {
    float S = as_[0] + as_[1] + as_[2] + as_[3];
    float C = ac_[0] + ac_[1] + ac_[2] + ac_[3];
    out[0] = S / fmaxf(C, 1.f);
  }
}

// ---------------- launch ----------------

extern "C" void kernel_launch(void* const* d_in, const int* in_sizes, int n_in,
                              void* d_out, int out_size, void* d_ws, size_t ws_size,
                              hipStream_t stream) {
  const int*   idx    = (const int*)d_in[0];
  const int*   tgt    = (const int*)d_in[1];
  const float* W_E    = (const float*)d_in[2];
  const float* start  = (const float*)d_in[3];
  const float* W_xh   = (const float*)d_in[4];
  const float* b_xh   = (const float*)d_in[5];
  const float* W_head = (const float*)d_in[6];
  const float* b_head = (const float*)d_in[7];

  // workspace layout (~314 MB). emb2 (dead after GEMM1) aliases hidden.
  // pm/ps (head-GEMM softmax partials) alias xproj (dead after rnn_scan).
  char* ws = (char*)d_ws;
  u16*      emb2   = (u16*)(ws);                                  // 32768x2048 bf16 = 128MB
  u16*      hidden = (u16*)(ws);                                  // 32768x2048 bf16 (alias)
  u16*      xproj  = (u16*)(ws + (size_t)128 * 1024 * 1024);      // [T][B][H] bf16 = 128MB
  float*    pm     = (float*)(ws + (size_t)128 * 1024 * 1024);    // 32768x64 f32 = 8MB (alias)
  float*    ps     = (float*)(ws + (size_t)136 * 1024 * 1024);    // 32768x64 f32 = 8MB (alias)
  u16*      WheadT = (u16*)(ws + (size_t)256 * 1024 * 1024);      // 8192x2048 bf16 = 32MB
  u16*      WhiT   = (u16*)(ws + (size_t)288 * 1024 * 1024);      // 2048x2048 bf16 = 8MB
  u16*      WloT   = (u16*)(ws + (size_t)296 * 1024 * 1024);      // 2048x2048 bf16 = 8MB
  u16*      WxT2   = (u16*)(ws + (size_t)304 * 1024 * 1024);      // 2048x2048 bf16 = 8MB
  u16*      hbuf   = (u16*)(ws + (size_t)312 * 1024 * 1024);      // 2x64x4096 bf16 = 1MB
  float*    nll    = (float*)(ws + (size_t)313 * 1024 * 1024);    // 32768 f32 = 128KB
  unsigned* sync   = (unsigned*)(ws + (size_t)313 * 1024 * 1024 + 128 * 1024); // 16KB tree

  embed_cast<<<Bb * Tt, 256, 0, stream>>>(W_E, idx, emb2);
  transpose_cast<<<dim3(Hh / 32, Ee / 32), 256, 0, stream>>>(W_xh, WxT2, Ee, Hh, 1);
  transpose_cast_hilo<<<dim3(Hh / 32, Hh / 32), 256, 0, stream>>>(W_xh + (size_t)Ee * Hh, WhiT, WloT, Hh, Hh);
  transpose_cast<<<dim3(Vv / 32, Hh / 32), 256, 0, stream>>>(W_head, WheadT, Hh, Vv, 0);
  h0_init<<<Bb, 256, 0, stream>>>(start, hbuf);
  hipMemsetAsync(sync, 0, 16384, stream);

  // xproj = [emb_hi|emb_lo] @ [Wx;Wx] + b_xh   (K=2048 effective)
  gemm_bt<1><<<dim3(256, 16), 256, 0, stream>>>(emb2, WxT2, b_xh, xproj, nullptr, nullptr,
                                                Bb * Tt, Hh, 2048);

  // persistent scan: 256 blocks (1/CU), 512 threads, Wh resident in LDS+VGPR
  rnn_scan<<<256, 512, 0, stream>>>(WhiT, WloT, xproj, hbuf, hidden, sync);

  // logits = hidden @ W_head + b_head -> d_out, + fused softmax partials
  gemm_bt<0><<<dim3(256, 64), 256, 0, stream>>>(hidden, WheadT, b_head, d_out, pm, ps,
                                                Bb * Tt, Vv, 2048);

  nll_from_partials<<<Bb * Tt / 4, 256, 0, stream>>>(pm, ps, (const float*)d_out, tgt, nll);
  loss_reduce<<<1, 256, 0, stream>>>(nll, tgt, (float*)d_out + ((size_t)out_size - 1));
}

// Round 8
// 4554.217 us; speedup vs baseline: 1.5248x; 1.2804x over previous
//
#include <hip/hip_runtime.h>
#include <hip/hip_bf16.h>
#include <math.h>
#include <stdint.h>

// RNN LM forward: B=64 T=512 V=8192 E=1024 H=2048
// out = [logits (B*T*V f32) | loss (1 f32)]
#define Bb 64
#define Tt 512
#define Vv 8192
#define Ee 1024
#define Hh 2048

typedef unsigned short u16;
typedef unsigned long long u64;
typedef __attribute__((ext_vector_type(8))) short bf16x8;      // 8 bf16 (4 VGPR)
typedef __attribute__((ext_vector_type(8))) _Float16 f16x8;    // 8 f16  (4 VGPR)
typedef __attribute__((ext_vector_type(4))) float f32x4;       // MFMA C/D frag

__device__ __forceinline__ u16 f2b(float f) {               // f32 -> bf16 RNE
  unsigned u = __float_as_uint(f);
  u += 0x7FFF + ((u >> 16) & 1);
  return (u16)(u >> 16);
}
__device__ __forceinline__ float b2f(u16 h) {
  return __uint_as_float(((unsigned)h) << 16);
}
__device__ __forceinline__ u16 f2h_bits(float f) {          // f32 -> f16 bits (v_cvt_f16_f32)
  union { _Float16 h; u16 u; } c;
  c.h = (_Float16)f;
  return c.u;
}
__device__ __forceinline__ u64 pack4(u16 a, u16 b, u16 c, u16 d) {
  return (u64)a | ((u64)b << 16) | ((u64)c << 32) | ((u64)d << 48);
}

// pipelined agent-coherent 16B load: issue-only (no waitcnt) — caller must
// s_waitcnt vmcnt(0) + sched_barrier before consuming. sc1 = agent scope,
// bypasses XCD-private L2 (reads the L3 coherence point directly).
__device__ __forceinline__ void gload16f(f16x8& dst, const void* addr) {
  asm volatile("global_load_dwordx4 %0, %1, off sc1"
               : "=v"(dst) : "v"(addr) : "memory");
}

__device__ __forceinline__ void gll16(const u16* g, u16* l) {
  __builtin_amdgcn_global_load_lds((__attribute__((address_space(1))) void*)g,
                                   (__attribute__((address_space(3))) void*)l, 16, 0, 0);
}

__device__ __forceinline__ float wave_max(float v) {
  #pragma unroll
  for (int d = 32; d; d >>= 1) v = fmaxf(v, __shfl_xor(v, d, 64));
  return v;
}
__device__ __forceinline__ float wave_sum(float v) {
  #pragma unroll
  for (int d = 32; d; d >>= 1) v += __shfl_xor(v, d, 64);
  return v;
}

// ---------------- prep kernels ----------------

// gather W_E rows by idx, split into bf16 hi|lo halves along K: emb2[m] = [hi(1024) | lo(1024)]
__global__ __launch_bounds__(256)
void embed_cast(const float* __restrict__ WE, const int* __restrict__ idx,
                u16* __restrict__ emb2) {
  const int m = blockIdx.x;
  const int row = idx[m];
  const float4 v = ((const float4*)(WE + (size_t)row * Ee))[threadIdx.x];
  ushort4 hi, lo;
  hi.x = f2b(v.x); lo.x = f2b(v.x - b2f(hi.x));
  hi.y = f2b(v.y); lo.y = f2b(v.y - b2f(hi.y));
  hi.z = f2b(v.z); lo.z = f2b(v.z - b2f(hi.z));
  hi.w = f2b(v.w); lo.w = f2b(v.w - b2f(hi.w));
  u16* d = emb2 + (size_t)m * 2048;
  ((ushort4*)d)[threadIdx.x] = hi;
  ((ushort4*)(d + Ee))[threadIdx.x] = lo;
}

// src[R][C] f32 -> dst[C][R<<dup] bf16 (transpose+cast hi); if dup, duplicate: [v | v]
__global__ __launch_bounds__(256)
void transpose_cast(const float* __restrict__ src, u16* __restrict__ dst,
                    int R, int C, int dup) {
  __shared__ float tile[32][33];
  const int bi = blockIdx.x;  // along C
  const int bj = blockIdx.y;  // along R
  const int tid = threadIdx.x;
  const int r  = tid >> 3;
  const int c4 = (tid & 7) * 4;
  float4 v = *(const float4*)(src + (size_t)(bj * 32 + r) * C + bi * 32 + c4);
  tile[r][c4 + 0] = v.x; tile[r][c4 + 1] = v.y;
  tile[r][c4 + 2] = v.z; tile[r][c4 + 3] = v.w;
  __syncthreads();
  const int RL = R << dup;
  ushort4 o;
  o.x = f2b(tile[c4 + 0][r]); o.y = f2b(tile[c4 + 1][r]);
  o.z = f2b(tile[c4 + 2][r]); o.w = f2b(tile[c4 + 3][r]);
  u16* d = dst + (size_t)(bi * 32 + r) * RL + bj * 32 + c4;
  *(ushort4*)d = o;
  if (dup) *(ushort4*)(d + R) = o;
}

// src[R][C] f32 -> dst[C][R] f16 bits (transpose + f16 cast) — for Wh.
// f16 (11-bit mantissa) is 8x more precise than the bf16 Wh that passed in r1.
__global__ __launch_bounds__(256)
void transpose_cast_f16(const float* __restrict__ src, u16* __restrict__ dst,
                        int R, int C) {
  __shared__ float tile[32][33];
  const int bi = blockIdx.x;  // along C
  const int bj = blockIdx.y;  // along R
  const int tid = threadIdx.x;
  const int r  = tid >> 3;
  const int c4 = (tid & 7) * 4;
  float4 v = *(const float4*)(src + (size_t)(bj * 32 + r) * C + bi * 32 + c4);
  tile[r][c4 + 0] = v.x; tile[r][c4 + 1] = v.y;
  tile[r][c4 + 2] = v.z; tile[r][c4 + 3] = v.w;
  __syncthreads();
  ushort4 o;
  o.x = f2h_bits(tile[c4 + 0][r]); o.y = f2h_bits(tile[c4 + 1][r]);
  o.z = f2h_bits(tile[c4 + 2][r]); o.w = f2h_bits(tile[c4 + 3][r]);
  *(ushort4*)(dst + (size_t)(bi * 32 + r) * R + bj * 32 + c4) = o;
}

// h0[b] = f16(start) per batch row (single 2048-wide f16 stream)
__global__ __launch_bounds__(256)
void h0_init(const float* __restrict__ start, u16* __restrict__ hbuf) {
  const int b = blockIdx.x;
  #pragma unroll
  for (int j = 0; j < 8; ++j) {
    int n = threadIdx.x * 8 + j;
    hbuf[(size_t)b * 2048 + n] = f2h_bits(start[n]);
  }
}

// ---------------- GEMM (m97-style 128x128 tile, BK=32, 4 waves) ----------------
// C[M x N] = A[M x K] * Bt[N x K]^T, bf16 inputs, f32 accum.
// MODE 0: out f32 at [row*N+col] + bias (head GEMM -> logits in d_out),
//         PLUS fused per-row softmax partials pm/ps[row][bn].
// MODE 1: out bf16 at [(t*B+b)*N+col] + bias, row = b*T+t  (xproj, t-major)
// XCD-aware block swizzle (T1): nwg % 8 == 0 for both call sites.
template <int MODE>
__global__ __launch_bounds__(256, 2)
void gemm_bt(const u16* __restrict__ A, const u16* __restrict__ Bt,
             const float* __restrict__ bias, void* __restrict__ outp,
             float* __restrict__ pm, float* __restrict__ ps,
             int M, int N, int K) {
  __shared__ u16 ldsA[128 * 32];
  __shared__ u16 ldsB[128 * 32];
  __shared__ float sm_[2][2][64];   // [wc][wr][row_local]  (MODE 0 partials)
  __shared__ float ss_[2][2][64];
  const int tid = threadIdx.x;
  const int lane = tid & 63;
  const int w = tid >> 6;
  const int wr = w >> 1, wc = w & 1;

  const int nwg = gridDim.x * gridDim.y;
  const int lin = blockIdx.y * gridDim.x + blockIdx.x;
  const int swz = (lin & 7) * (nwg >> 3) + (lin >> 3);
  const int bm = swz % gridDim.x;
  const int bn = swz / gridDim.x;

  const int srow = w * 32 + (lane >> 2);
  const int scol = (lane & 3) * 8;
  const u16* a0 = A + (size_t)(bm * 128 + srow) * K + scol;
  const u16* b0 = Bt + (size_t)(bn * 128 + srow) * K + scol;
  u16* lA0 = ldsA + w * 1024;
  u16* lA1 = ldsA + w * 1024 + 512;
  u16* lB0 = ldsB + w * 1024;
  u16* lB1 = ldsB + w * 1024 + 512;

  f32x4 acc[4][4];
  #pragma unroll
  for (int m = 0; m < 4; ++m)
    #pragma unroll
    for (int n = 0; n < 4; ++n)
      acc[m][n] = (f32x4){0.f, 0.f, 0.f, 0.f};

  const int nk = K >> 5;
  for (int kt = 0; kt < nk; ++kt) {
    __syncthreads();
    const u16* ak = a0 + kt * 32;
    const u16* bk = b0 + kt * 32;
    gll16(ak, lA0);
    gll16(ak + 16 * (size_t)K, lA1);
    gll16(bk, lB0);
    gll16(bk + 16 * (size_t)K, lB1);
    __syncthreads();
    bf16x8 af[4], bfr[4];
    #pragma unroll
    for (int i = 0; i < 4; ++i) {
      af[i]  = *(const bf16x8*)&ldsA[(wr * 64 + i * 16 + (lane & 15)) * 32 + (lane >> 4) * 8];
      bfr[i] = *(const bf16x8*)&ldsB[(wc * 64 + i * 16 + (lane & 15)) * 32 + (lane >> 4) * 8];
    }
    #pragma unroll
    for (int m = 0; m < 4; ++m)
      #pragma unroll
      for (int n = 0; n < 4; ++n)
        acc[m][n] = __builtin_amdgcn_mfma_f32_16x16x32_bf16(af[m], bfr[n], acc[m][n], 0, 0, 0);
  }

  // epilogue: D col = lane&15, row = (lane>>4)*4 + q
  const int r0 = bm * 128 + wr * 64 + (lane >> 4) * 4;
  const int c0 = bn * 128 + wc * 64 + (lane & 15);

  if (MODE == 0) {
    float bv[4];
    #pragma unroll
    for (int n = 0; n < 4; ++n) bv[n] = bias[c0 + n * 16];
    #pragma unroll
    for (int m = 0; m < 4; ++m) {
      #pragma unroll
      for (int q = 0; q < 4; ++q) {
        const int row = r0 + m * 16 + q;
        float v[4];
        float mx = -1e30f;
        #pragma unroll
        for (int n = 0; n < 4; ++n) {
          v[n] = acc[m][n][q] + bv[n];
          ((float*)outp)[(size_t)row * N + c0 + n * 16] = v[n];
          mx = fmaxf(mx, v[n]);
        }
        #pragma unroll
        for (int d = 1; d < 16; d <<= 1) mx = fmaxf(mx, __shfl_xor(mx, d, 64));
        float se = 0.f;
        #pragma unroll
        for (int n = 0; n < 4; ++n) se += expf(v[n] - mx);
        #pragma unroll
        for (int d = 1; d < 16; d <<= 1) se += __shfl_xor(se, d, 64);
        if ((lane & 15) == 0) {
          const int rl = m * 16 + (lane >> 4) * 4 + q;
          sm_[wc][wr][rl] = mx;
          ss_[wc][wr][rl] = se;
        }
      }
    }
    __syncthreads();
    if (w < 2) {   // wave w combines wc halves for rows [bm*128 + w*64, +64)
      float m0 = sm_[0][w][lane], m1 = sm_[1][w][lane];
      float s0 = ss_[0][w][lane], s1 = ss_[1][w][lane];
      float Mx = fmaxf(m0, m1);
      float S = s0 * expf(m0 - Mx) + s1 * expf(m1 - Mx);
      const int row = bm * 128 + w * 64 + lane;
      pm[(size_t)row * 64 + bn] = Mx;
      ps[(size_t)row * 64 + bn] = S;
    }
  } else {
    #pragma unroll
    for (int n = 0; n < 4; ++n) {
      const int col = c0 + n * 16;
      const float bv = bias[col];
      #pragma unroll
      for (int m = 0; m < 4; ++m) {
        #pragma unroll
        for (int q = 0; q < 4; ++q) {
          const int row = r0 + m * 16 + q;
          float v = acc[m][n][q] + bv;
          const int b = row >> 9, t = row & 511;   // row = b*T + t
          ((u16*)outp)[((size_t)t * Bb + b) * N + col] = f2b(v);
        }
      }
    }
  }
}

// ---------------- persistent recurrence scan ----------------
// 256 blocks x 512 thr (8 waves), 1 block/CU (144KB LDS).
// Block bid: group g = bid>>6 owns batch rows [16g,16g+16); colg = bid&63 owns
// H-cols [colg*32, colg*32+32). Wh (f16, 32 cols x 2048 K = 128KB) in LDS for
// all 512 steps. h = SINGLE f16 stream (r8: halves the 32MB/step L3 broadcast
// that was the bandwidth floor; f16 h err 2.4e-4/step is damped by the rho~0.9
// recurrence; f16 Wh is 8x more precise than r1's passing bf16 Wh).
// h ping-pongs in global via sc1 (direct-to-L3) accesses.
//
// Sync lessons (A/B-measured r2-r7):
//  * agent-scope acq/rel = whole-L2 wb/inv every step -> RELAXED everywhere (r5)
//  * flag-array poll regresses (r3, r6); 2-level tree adds an RTT (r7) ->
//    SINGLE monotonic counter, pollers poll the COUNTER directly (r8: the
//    last arrival RMW is itself the release; saves the generation-store RTT).
// Publication: producers' sc1 h-stores complete at L3 before tid0's arrival
// RMW issues (syncthreads drains vmcnt; same-wave order); consumers' h loads
// issue only after the cnt poll exits (branch + s_barrier).
__global__ __launch_bounds__(512, 2)
void rnn_scan(const u16* __restrict__ WhT, const u16* __restrict__ xp,
              u16* __restrict__ hbuf, u16* __restrict__ hidden,
              unsigned* __restrict__ sync) {
  __shared__ u16 whi[65536];     // 128KB f16 bits: frag(c2,kt) base (c2*64+kt)*512 u16
  __shared__ float red[4096];    // 16KB: 16 slots (frag0: w, frag1: 8+w) x 256 f32

  const int bid = blockIdx.x;
  const int g = bid >> 6;
  const int colg = bid & 63;
  const int rowbase = g * 16;
  const int col0 = colg * 32;
  const int tid = threadIdx.x;
  const int lane = tid & 63;
  const int w = tid >> 6;        // wave = K-slice index, 0..7

  // ---- preload Wh (f16) into LDS (one-time) ----
  for (int i = tid; i < 8192; i += 512) {
    const int ch = i & 3;
    const int cl = (i >> 2) & 15;
    const int kt = (i >> 6) & 63;
    const int c2 = (i >> 12) & 1;
    bf16x8 v = *(const bf16x8*)(WhT + (size_t)(col0 + c2 * 16 + cl) * 2048 + kt * 32 + ch * 8);
    *(bf16x8*)&whi[(size_t)(c2 * 64 + kt) * 512 + ch * 128 + cl * 8] = v;
  }
  __syncthreads();

  unsigned* cnt = sync + g * 64;        // monotonic arrival counter (one per group)
  bool dead = false;

  const int hrow = rowbase + (lane & 15);

  // xp prefetch for t=0 (epilogue waves only)
  ushort4 xv = {0, 0, 0, 0};
  if (w < 2)
    xv = *(const ushort4*)(xp + (size_t)hrow * 2048 + col0 + w * 16 + (lane >> 4) * 4);

  for (int t = 0; t < Tt; ++t) {
    const u16* hp = hbuf + (size_t)(t & 1) * (64 * 2048);
    u16*       hn = hbuf + (size_t)((t + 1) & 1) * (64 * 2048);

    // ---- batched h loads for this wave's K-slice: 8 x 16B, all in flight ----
    f16x8 qh[8];
    const u16* hb = hp + (size_t)hrow * 2048 + (lane >> 4) * 8;
    #pragma unroll
    for (int kt = 0; kt < 8; ++kt)
      gload16f(qh[kt], hb + (w * 8 + kt) * 32);
    asm volatile("s_waitcnt vmcnt(0)" ::: "memory");
    __builtin_amdgcn_sched_barrier(0);   // rule #18: pin MFMAs below the waitcnt

    f32x4 a0 = (f32x4){0.f, 0.f, 0.f, 0.f};
    f32x4 a1 = (f32x4){0.f, 0.f, 0.f, 0.f};
    #pragma unroll
    for (int kt = 0; kt < 8; ++kt) {
      const int ktG = w * 8 + kt;
      f16x8 w0 = *(const f16x8*)&whi[(size_t)(0 * 64 + ktG) * 512 + (lane >> 4) * 128 + (lane & 15) * 8];
      f16x8 w1 = *(const f16x8*)&whi[(size_t)(1 * 64 + ktG) * 512 + (lane >> 4) * 128 + (lane & 15) * 8];
      a0 = __builtin_amdgcn_mfma_f32_16x16x32_f16(w0, qh[kt], a0, 0, 0, 0);
      a1 = __builtin_amdgcn_mfma_f32_16x16x32_f16(w1, qh[kt], a1, 0, 0, 0);
    }

    // ---- K-reduce across waves: all waves export both frags ----
    *(f32x4*)&red[(w) * 256 + lane * 4]     = a0;   // frag0 bank: slots 0..7
    *(f32x4*)&red[(8 + w) * 256 + lane * 4] = a1;   // frag1 bank: slots 8..15
    __syncthreads();

    // ---- epilogue split: wave w<2 owns frag c2=w (cols col0+w*16 .. +16) ----
    if (w < 2) {
      f32x4 ac = (f32x4){0.f, 0.f, 0.f, 0.f};
      #pragma unroll
      for (int j = 0; j < 8; ++j)
        ac += *(const f32x4*)&red[(w * 8 + j) * 256 + lane * 4];
      const int cl0 = (lane >> 4) * 4;
      u16 hf[4], hbv[4];
      #pragma unroll
      for (int qq = 0; qq < 4; ++qq) {
        float v = tanhf(ac[qq] + b2f(((const u16*)&xv)[qq]));
        hf[qq]  = f2h_bits(v);   // f16 for the recurrence stream
        hbv[qq] = f2b(v);        // bf16 for the head GEMM input
      }
      u64 ph = pack4(hf[0], hf[1], hf[2], hf[3]);
      u64 pb = pack4(hbv[0], hbv[1], hbv[2], hbv[3]);
      u16* hd = hn + (size_t)hrow * 2048 + col0 + w * 16 + cl0;
      __hip_atomic_store((u64*)hd, ph, __ATOMIC_RELAXED, __HIP_MEMORY_SCOPE_AGENT);
      *(u64*)(hidden + ((size_t)hrow * Tt + t) * Hh + col0 + w * 16 + cl0) = pb;
    }

    // ---- group barrier: relaxed monotonic counter, poll the counter itself ----
    __syncthreads();                    // drains vmcnt -> h stores complete at L3
    // prefetch next step's xp (barrier-independent; overlaps arrival/detect)
    if (w < 2 && t + 1 < Tt)
      xv = *(const ushort4*)(xp + ((size_t)(t + 1) * Bb + hrow) * 2048 + col0 + w * 16 + (lane >> 4) * 4);
    if (tid == 0) {
      unsigned old = __hip_atomic_fetch_add(cnt, 1u, __ATOMIC_RELAXED, __HIP_MEMORY_SCOPE_AGENT);
      if (old != (unsigned)(t * 64 + 63) && !dead) {   // not the last arriver
        unsigned polls = 0;
        while (__hip_atomic_load(cnt, __ATOMIC_RELAXED, __HIP_MEMORY_SCOPE_AGENT)
               < (unsigned)((t + 1) * 64)) {
          if (++polls > 4000000u) { dead = true; break; }   // anti-hang escape
        }
      }
    }
    __syncthreads();
  }
}

// ---------------- loss ----------------

// per-row NLL from fused GEMM partials: M = max_l pm, S = sum_l ps*exp(pm-M),
// nll = M + log S - logits[r][tgt].  One wave per row.
__global__ __launch_bounds__(256)
void nll_from_partials(const float* __restrict__ pm, const float* __restrict__ ps,
                       const float* __restrict__ logits, const int* __restrict__ tgt,
                       float* __restrict__ nll) {
  const int r = blockIdx.x * 4 + (threadIdx.x >> 6);
  const int lane = threadIdx.x & 63;
  float m = pm[(size_t)r * 64 + lane];
  float s = ps[(size_t)r * 64 + lane];
  float M = wave_max(m);
  float S = wave_sum(s * expf(m - M));
  if (lane == 0) {
    const int tg = tgt[r];
    float o = 0.f;
    if (tg != -1) o = M + logf(S) - logits[(size_t)r * Vv + tg];
    nll[r] = o;
  }
}

__global__ __launch_bounds__(256)
void loss_reduce(const float* __restrict__ nll, const int* __restrict__ tgt,
                 float* __restrict__ out) {
  const int tid = threadIdx.x;
  float s = 0.f, c = 0.f;
  for (int i = tid; i < Bb * Tt; i += 256) {
    s += nll[i];
    c += (tgt[i] != -1) ? 1.f : 0.f;
  }
  s = wave_sum(s);
  c = wave_sum(c);
  __shared__ float as_[4], ac_[4];
  const int w = tid >> 6;
  if ((tid & 63) == 0) { as_[w] = s; ac_[w] = c; }
  __syncthreads();
  if (tid == 0) {
    float S = as_[0] + as_[1] + as_[2] + as_[3];
    float C = ac_[0] + ac_[1] + ac_[2] + ac_[3];
    out[0] = S / fmaxf(C, 1.f);
  }
}

// ---------------- launch ----------------

extern "C" void kernel_launch(void* const* d_in, const int* in_sizes, int n_in,
                              void* d_out, int out_size, void* d_ws, size_t ws_size,
                              hipStream_t stream) {
  const int*   idx    = (const int*)d_in[0];
  const int*   tgt    = (const int*)d_in[1];
  const float* W_E    = (const float*)d_in[2];
  const float* start  = (const float*)d_in[3];
  const float* W_xh   = (const float*)d_in[4];
  const float* b_xh   = (const float*)d_in[5];
  const float* W_head = (const float*)d_in[6];
  const float* b_head = (const float*)d_in[7];

  // workspace layout (~314 MB). emb2 (dead after GEMM1) aliases hidden.
  // pm/ps (head-GEMM softmax partials) alias xproj (dead after rnn_scan).
  char* ws = (char*)d_ws;
  u16*      emb2   = (u16*)(ws);                                  // 32768x2048 bf16 = 128MB
  u16*      hidden = (u16*)(ws);                                  // 32768x2048 bf16 (alias)
  u16*      xproj  = (u16*)(ws + (size_t)128 * 1024 * 1024);      // [T][B][H] bf16 = 128MB
  float*    pm     = (float*)(ws + (size_t)128 * 1024 * 1024);    // 32768x64 f32 = 8MB (alias)
  float*    ps     = (float*)(ws + (size_t)136 * 1024 * 1024);    // 32768x64 f32 = 8MB (alias)
  u16*      WheadT = (u16*)(ws + (size_t)256 * 1024 * 1024);      // 8192x2048 bf16 = 32MB
  u16*      WhT    = (u16*)(ws + (size_t)288 * 1024 * 1024);      // 2048x2048 f16 = 8MB
  u16*      WxT2   = (u16*)(ws + (size_t)304 * 1024 * 1024);      // 2048x2048 bf16 = 8MB
  u16*      hbuf   = (u16*)(ws + (size_t)312 * 1024 * 1024);      // 2x64x2048 f16 = 512KB
  float*    nll    = (float*)(ws + (size_t)313 * 1024 * 1024);    // 32768 f32 = 128KB
  unsigned* sync   = (unsigned*)(ws + (size_t)313 * 1024 * 1024 + 128 * 1024); // 1KB

  embed_cast<<<Bb * Tt, 256, 0, stream>>>(W_E, idx, emb2);
  transpose_cast<<<dim3(Hh / 32, Ee / 32), 256, 0, stream>>>(W_xh, WxT2, Ee, Hh, 1);
  transpose_cast_f16<<<dim3(Hh / 32, Hh / 32), 256, 0, stream>>>(W_xh + (size_t)Ee * Hh, WhT, Hh, Hh);
  transpose_cast<<<dim3(Vv / 32, Hh / 32), 256, 0, stream>>>(W_head, WheadT, Hh, Vv, 0);
  h0_init<<<Bb, 256, 0, stream>>>(start, hbuf);
  hipMemsetAsync(sync, 0, 1024, stream);

  // xproj = [emb_hi|emb_lo] @ [Wx;Wx] + b_xh   (K=2048 effective)
  gemm_bt<1><<<dim3(256, 16), 256, 0, stream>>>(emb2, WxT2, b_xh, xproj, nullptr, nullptr,
                                                Bb * Tt, Hh, 2048);

  // persistent scan: 256 blocks (1/CU), 512 threads, Wh resident in LDS (f16)
  rnn_scan<<<256, 512, 0, stream>>>(WhT, xproj, hbuf, hidden, sync);

  // logits = hidden @ W_head + b_head -> d_out, + fused softmax partials
  gemm_bt<0><<<dim3(256, 64), 256, 0, stream>>>(hidden, WheadT, b_head, d_out, pm, ps,
                                                Bb * Tt, Vv, 2048);

  nll_from_partials<<<Bb * Tt / 4, 256, 0, stream>>>(pm, ps, (const float*)d_out, tgt, nll);
  loss_reduce<<<1, 256, 0, stream>>>(nll, tgt, (float*)d_out + ((size_t)out_size - 1));
}